// Round 1
// baseline (918.063 us; speedup 1.0000x reference)
//
#include <hip/hip_runtime.h>
#include <math.h>

// Problem constants (B, D_e, D_o, T, H, W) = (4, 128, 512, 8, 32, 32)
constexpr int B_  = 4;
constexpr int DE_ = 128;
constexpr int DO_ = 512;
constexpr int N_  = 8192;   // T*H*W (memory keys)
constexpr int M_  = 1024;   // H*W   (query positions)
constexpr int NCHUNK_ = 32; // softmax N-chunks (8192/256)

// ---------------------------------------------------------------------------
// Kernel 1: S[b,n,m] = scale * sum_d mi[b,d,n] * qi[b,d,m]
// C = A^T * B with A=[K=128,N], B=[K=128,M]. 64x64 tile, 4x4 per thread.
// S written into the prob region of d_out (used as scratch, normalized later).
// ---------------------------------------------------------------------------
__global__ __launch_bounds__(256) void k_scores(const float* __restrict__ mi,
                                                const float* __restrict__ qi,
                                                float* __restrict__ S) {
    __shared__ float As[32][64];  // [k][n] — stride-1 store, broadcast read
    __shared__ float Bs[32][64];  // [k][m]
    const int m0 = blockIdx.x * 64;
    const int n0 = blockIdx.y * 64;
    const int b  = blockIdx.z;
    const int tid = threadIdx.x;
    const int tx = tid & 15;   // m fragment group (4 cols each)
    const int ty = tid >> 4;   // n fragment group (4 rows each)

    const float* miB = mi + (size_t)b * DE_ * N_;
    const float* qiB = qi + (size_t)b * DE_ * M_;

    float acc[4][4] = {};

    for (int k0 = 0; k0 < DE_; k0 += 32) {
        #pragma unroll
        for (int t = 0; t < 8; ++t) {
            int e = tid + t * 256;
            int kk = e >> 6, nn = e & 63;
            As[kk][nn] = miB[(size_t)(k0 + kk) * N_ + n0 + nn];
            Bs[kk][nn] = qiB[(size_t)(k0 + kk) * M_ + m0 + nn];
        }
        __syncthreads();
        #pragma unroll
        for (int kk = 0; kk < 32; ++kk) {
            float a[4], p[4];
            #pragma unroll
            for (int i = 0; i < 4; ++i) a[i] = As[kk][ty * 4 + i];
            #pragma unroll
            for (int j = 0; j < 4; ++j) p[j] = Bs[kk][tx * 4 + j];
            #pragma unroll
            for (int i = 0; i < 4; ++i)
                #pragma unroll
                for (int j = 0; j < 4; ++j)
                    acc[i][j] = fmaf(a[i], p[j], acc[i][j]);
        }
        __syncthreads();
    }

    const float scale = 0.08838834764831845f;  // 1/sqrt(128)
    float* Sp = S + (size_t)b * N_ * M_;
    #pragma unroll
    for (int i = 0; i < 4; ++i) {
        float4 v = make_float4(acc[i][0] * scale, acc[i][1] * scale,
                               acc[i][2] * scale, acc[i][3] * scale);
        *(float4*)&Sp[(size_t)(n0 + ty * 4 + i) * M_ + m0 + tx * 4] = v;
    }
}

// ---------------------------------------------------------------------------
// Kernel 2: per-(b,m) column partial softmax stats over a 256-row N chunk.
// Each thread owns one column (online max/sum). Coalesced row reads.
// ---------------------------------------------------------------------------
__global__ __launch_bounds__(256) void k_colstats(const float* __restrict__ S,
                                                  float* __restrict__ pmax,
                                                  float* __restrict__ psum) {
    const int m = blockIdx.x * 256 + threadIdx.x;
    const int c = blockIdx.y;  // N chunk
    const int b = blockIdx.z;
    const float* Sp = S + (size_t)b * N_ * M_ + (size_t)c * 256 * M_ + m;
    float mx = -INFINITY, sm = 0.f;
    for (int n = 0; n < 256; ++n) {
        float x = Sp[(size_t)n * M_];
        float mnew = fmaxf(mx, x);
        sm = sm * __expf(mx - mnew) + __expf(x - mnew);
        mx = mnew;
    }
    size_t idx = ((size_t)b * NCHUNK_ + c) * M_ + m;
    pmax[idx] = mx;
    psum[idx] = sm;
}

// ---------------------------------------------------------------------------
// Kernel 3: combine the 32 chunk partials per column -> gmax, 1/sum.
// ---------------------------------------------------------------------------
__global__ __launch_bounds__(256) void k_reduce(const float* __restrict__ pmax,
                                                const float* __restrict__ psum,
                                                float* __restrict__ gmax,
                                                float* __restrict__ ginv) {
    const int g = blockIdx.x * 256 + threadIdx.x;  // b*M + m
    const int b = g >> 10;
    const int m = g & (M_ - 1);
    float pm[NCHUNK_];
    float mx = -INFINITY;
    #pragma unroll
    for (int c = 0; c < NCHUNK_; ++c) {
        pm[c] = pmax[((size_t)b * NCHUNK_ + c) * M_ + m];
        mx = fmaxf(mx, pm[c]);
    }
    float sm = 0.f;
    #pragma unroll
    for (int c = 0; c < NCHUNK_; ++c) {
        sm += psum[((size_t)b * NCHUNK_ + c) * M_ + m] * __expf(pm[c] - mx);
    }
    gmax[g] = mx;
    ginv[g] = 1.0f / sm;
}

// ---------------------------------------------------------------------------
// Kernel 4: in-place normalize: prob = exp(S - gmax[b,m]) * ginv[b,m]
// float4 grid-stride; a float4 never crosses an m-row boundary (M%4==0).
// ---------------------------------------------------------------------------
__global__ __launch_bounds__(256) void k_normalize(float* __restrict__ S,
                                                   const float* __restrict__ gmax,
                                                   const float* __restrict__ ginv) {
    const size_t total4 = (size_t)B_ * N_ * M_ / 4;
    for (size_t i = (size_t)blockIdx.x * 256 + threadIdx.x; i < total4;
         i += (size_t)gridDim.x * 256) {
        size_t e = i * 4;
        int b = (int)(e / ((size_t)N_ * M_));
        int m = (int)(e & (M_ - 1));
        float4 v = ((float4*)S)[i];
        float4 gm = *(const float4*)&gmax[b * M_ + m];
        float4 gi = *(const float4*)&ginv[b * M_ + m];
        v.x = __expf(v.x - gm.x) * gi.x;
        v.y = __expf(v.y - gm.y) * gi.y;
        v.z = __expf(v.z - gm.z) * gi.z;
        v.w = __expf(v.w - gm.w) * gi.w;
        ((float4*)S)[i] = v;
    }
}

// ---------------------------------------------------------------------------
// Kernel 5: memory[b,d,m] = sum_n mo[b,d,n] * prob[b,n,m]
// C = A * P, A=[512,8192], P=[8192,1024]. 64x64 tile, 4x4 per thread.
// A tile stored transposed in LDS ([kk][dd], pad to 68 to keep 16B row align
// and break the store conflict). Writes directly into the concat out layout.
// ---------------------------------------------------------------------------
__global__ __launch_bounds__(256) void k_pv(const float* __restrict__ mo,
                                            const float* __restrict__ P,
                                            float* __restrict__ out) {
    __shared__ float As[32][68];  // [kk(n)][dd] transposed, padded (68*4B=17*16B)
    __shared__ float Ps[32][64];  // [kk(n)][mm]
    const int m0 = blockIdx.x * 64;
    const int d0 = blockIdx.y * 64;
    const int b  = blockIdx.z;
    const int tid = threadIdx.x;
    const int tx = tid & 15;   // m fragment
    const int ty = tid >> 4;   // d fragment

    const float* moB = mo + (size_t)b * DO_ * N_;
    const float* PB  = P  + (size_t)b * N_ * M_;

    float acc[4][4] = {};

    for (int n0 = 0; n0 < N_; n0 += 32) {
        #pragma unroll
        for (int t = 0; t < 8; ++t) {
            int e = tid + t * 256;
            int dd = e >> 5, nn = e & 31;
            As[nn][dd] = moB[(size_t)(d0 + dd) * N_ + n0 + nn];
        }
        #pragma unroll
        for (int t = 0; t < 8; ++t) {
            int e = tid + t * 256;
            int kk = e >> 6, mm = e & 63;
            Ps[kk][mm] = PB[(size_t)(n0 + kk) * M_ + m0 + mm];
        }
        __syncthreads();
        #pragma unroll
        for (int kk = 0; kk < 32; ++kk) {
            float a[4], p[4];
            #pragma unroll
            for (int i = 0; i < 4; ++i) a[i] = As[kk][ty * 4 + i];
            #pragma unroll
            for (int j = 0; j < 4; ++j) p[j] = Ps[kk][tx * 4 + j];
            #pragma unroll
            for (int i = 0; i < 4; ++i)
                #pragma unroll
                for (int j = 0; j < 4; ++j)
                    acc[i][j] = fmaf(a[i], p[j], acc[i][j]);
        }
        __syncthreads();
    }

    // out layout: [B][2*DO][M]; memory occupies channels [0,DO)
    float* outB = out + (size_t)b * 2 * DO_ * M_;
    #pragma unroll
    for (int i = 0; i < 4; ++i) {
        float4 v = make_float4(acc[i][0], acc[i][1], acc[i][2], acc[i][3]);
        *(float4*)&outB[(size_t)(d0 + ty * 4 + i) * M_ + m0 + tx * 4] = v;
    }
}

// ---------------------------------------------------------------------------
// Kernel 6: copy query_out into channels [DO, 2*DO) of out.
// ---------------------------------------------------------------------------
__global__ __launch_bounds__(256) void k_copyq(const float* __restrict__ q,
                                               float* __restrict__ out) {
    const size_t i = (size_t)blockIdx.x * 256 + threadIdx.x;  // float4 index
    const size_t e = i * 4;
    const int b = (int)(e / ((size_t)DO_ * M_));
    const size_t r = e % ((size_t)DO_ * M_);
    float4 v = *(const float4*)&q[e];
    *(float4*)&out[(size_t)b * 2 * DO_ * M_ + (size_t)DO_ * M_ + r] = v;
}

// ---------------------------------------------------------------------------
extern "C" void kernel_launch(void* const* d_in, const int* in_sizes, int n_in,
                              void* d_out, int out_size, void* d_ws, size_t ws_size,
                              hipStream_t stream) {
    const float* mi = (const float*)d_in[0];  // memory_in  [B,128,8192]
    const float* mo = (const float*)d_in[1];  // memory_out [B,512,8192]
    const float* qi = (const float*)d_in[2];  // query_in   [B,128,1024]
    const float* qo = (const float*)d_in[3];  // query_out  [B,512,1024]

    float* out  = (float*)d_out;                       // [B,1024,1024]
    float* prob = out + (size_t)B_ * 2 * DO_ * M_;     // [B,8192,1024]

    // workspace partials (~1.1 MB)
    float* pmax = (float*)d_ws;                        // [B,32,M]
    float* psum = pmax + (size_t)B_ * NCHUNK_ * M_;    // [B,32,M]
    float* gmax = psum + (size_t)B_ * NCHUNK_ * M_;    // [B,M]
    float* ginv = gmax + (size_t)B_ * M_;              // [B,M]

    k_scores   <<<dim3(M_ / 64, N_ / 64, B_), 256, 0, stream>>>(mi, qi, prob);
    k_colstats <<<dim3(M_ / 256, NCHUNK_, B_), 256, 0, stream>>>(prob, pmax, psum);
    k_reduce   <<<dim3(B_ * M_ / 256), 256, 0, stream>>>(pmax, psum, gmax, ginv);
    k_normalize<<<dim3(2048), 256, 0, stream>>>(prob, gmax, ginv);
    k_pv       <<<dim3(M_ / 64, DO_ / 64, B_), 256, 0, stream>>>(mo, prob, out);
    k_copyq    <<<dim3((B_ * DO_ * M_ / 4) / 256), 256, 0, stream>>>(qo, out);
}

// Round 6
// 467.686 us; speedup vs baseline: 1.9630x; 1.9630x over previous
//
#include <hip/hip_runtime.h>
#include <math.h>
#include <stdint.h>

// Problem constants (B, D_e, D_o, T, H, W) = (4, 128, 512, 8, 32, 32)
constexpr int B_  = 4;
constexpr int DE_ = 128;
constexpr int DO_ = 512;
constexpr int N_  = 8192;   // T*H*W (memory keys)
constexpr int M_  = 1024;   // H*W   (query positions)
constexpr int NCHUNK_ = 32; // softmax N-chunks
constexpr int SPLITK_ = 4;  // k_pv split-K factor
constexpr int KCHUNK_ = N_ / SPLITK_;  // 2048

typedef __attribute__((ext_vector_type(8))) short bf16x8;
typedef __attribute__((ext_vector_type(8))) unsigned short u16x8;
typedef __attribute__((ext_vector_type(4))) float f32x4;

static __device__ __forceinline__ uint16_t f2bf(float f) {
    uint32_t u = __builtin_bit_cast(uint32_t, f);
    u += 0x7fffu + ((u >> 16) & 1u);   // round-to-nearest-even
    return (uint16_t)(u >> 16);
}

// ---------------------------------------------------------------------------
// Kernel 1: S[b,n,m] = scale * sum_d mi[b,d,n] * qi[b,d,m]   (fp32)
// ---------------------------------------------------------------------------
__global__ __launch_bounds__(256) void k_scores(const float* __restrict__ mi,
                                                const float* __restrict__ qi,
                                                float* __restrict__ S) {
    __shared__ float As[32][64];
    __shared__ float Bs[32][64];
    const int m0 = blockIdx.x * 64;
    const int n0 = blockIdx.y * 64;
    const int b  = blockIdx.z;
    const int tid = threadIdx.x;
    const int tx = tid & 15;
    const int ty = tid >> 4;

    const float* miB = mi + (size_t)b * DE_ * N_;
    const float* qiB = qi + (size_t)b * DE_ * M_;

    float acc[4][4] = {};

    for (int k0 = 0; k0 < DE_; k0 += 32) {
        #pragma unroll
        for (int t = 0; t < 8; ++t) {
            int e = tid + t * 256;
            int kk = e >> 6, nn = e & 63;
            As[kk][nn] = miB[(size_t)(k0 + kk) * N_ + n0 + nn];
            Bs[kk][nn] = qiB[(size_t)(k0 + kk) * M_ + m0 + nn];
        }
        __syncthreads();
        #pragma unroll
        for (int kk = 0; kk < 32; ++kk) {
            float a[4], p[4];
            #pragma unroll
            for (int i = 0; i < 4; ++i) a[i] = As[kk][ty * 4 + i];
            #pragma unroll
            for (int j = 0; j < 4; ++j) p[j] = Bs[kk][tx * 4 + j];
            #pragma unroll
            for (int i = 0; i < 4; ++i)
                #pragma unroll
                for (int j = 0; j < 4; ++j)
                    acc[i][j] = fmaf(a[i], p[j], acc[i][j]);
        }
        __syncthreads();
    }

    const float scale = 0.08838834764831845f;  // 1/sqrt(128)
    float* Sp = S + (size_t)b * N_ * M_;
    #pragma unroll
    for (int i = 0; i < 4; ++i) {
        float4 v = make_float4(acc[i][0] * scale, acc[i][1] * scale,
                               acc[i][2] * scale, acc[i][3] * scale);
        *(float4*)&Sp[(size_t)(n0 + ty * 4 + i) * M_ + m0 + tx * 4] = v;
    }
}

// ---------------------------------------------------------------------------
// Kernel 2: per-(b,m) column partial softmax stats over a 256-row N chunk.
// ---------------------------------------------------------------------------
__global__ __launch_bounds__(256) void k_colstats(const float* __restrict__ S,
                                                  float* __restrict__ pmax,
                                                  float* __restrict__ psum) {
    const int m = blockIdx.x * 256 + threadIdx.x;
    const int c = blockIdx.y;
    const int b = blockIdx.z;
    const float* Sp = S + (size_t)b * N_ * M_ + (size_t)c * 256 * M_ + m;
    float mx = -INFINITY, sm = 0.f;
    for (int n = 0; n < 256; ++n) {
        float x = Sp[(size_t)n * M_];
        float mnew = fmaxf(mx, x);
        sm = sm * __expf(mx - mnew) + __expf(x - mnew);
        mx = mnew;
    }
    size_t idx = ((size_t)b * NCHUNK_ + c) * M_ + m;
    pmax[idx] = mx;
    psum[idx] = sm;
}

// ---------------------------------------------------------------------------
// Kernel 3: combine chunk partials -> gmax, 1/sum.
// ---------------------------------------------------------------------------
__global__ __launch_bounds__(256) void k_reduce(const float* __restrict__ pmax,
                                                const float* __restrict__ psum,
                                                float* __restrict__ gmax,
                                                float* __restrict__ ginv) {
    const int g = blockIdx.x * 256 + threadIdx.x;
    const int b = g >> 10;
    const int m = g & (M_ - 1);
    float pm[NCHUNK_];
    float mx = -INFINITY;
    #pragma unroll
    for (int c = 0; c < NCHUNK_; ++c) {
        pm[c] = pmax[((size_t)b * NCHUNK_ + c) * M_ + m];
        mx = fmaxf(mx, pm[c]);
    }
    float sm = 0.f;
    #pragma unroll
    for (int c = 0; c < NCHUNK_; ++c) {
        sm += psum[((size_t)b * NCHUNK_ + c) * M_ + m] * __expf(pm[c] - mx);
    }
    gmax[g] = mx;
    ginv[g] = 1.0f / sm;
}

// ---------------------------------------------------------------------------
// Kernel 4 (fast path): normalize in place AND emit transposed bf16 copy
// Pt[b][m][n] for the MFMA PV kernel. 64(n) x 64(m) tile via LDS.
// ---------------------------------------------------------------------------
__global__ __launch_bounds__(256) void k_normalize_t(float* __restrict__ S,
                                                     const float* __restrict__ gmax,
                                                     const float* __restrict__ ginv,
                                                     uint16_t* __restrict__ Pt) {
    __shared__ float T[64][65];   // [n_local][m_local], stride 65 (bank-safe)
    const int m0 = blockIdx.x * 64;
    const int n0 = blockIdx.y * 64;
    const int b  = blockIdx.z;
    const int t  = threadIdx.x;
    const int c  = t & 15;        // m quad
    const int rr = t >> 4;        // 0..15

    float4 gm = *(const float4*)&gmax[b * M_ + m0 + c * 4];
    float4 gi = *(const float4*)&ginv[b * M_ + m0 + c * 4];
    float* Sp = S + (size_t)b * N_ * M_;

    #pragma unroll
    for (int it = 0; it < 4; ++it) {
        int r = rr + it * 16;
        size_t idx = (size_t)(n0 + r) * M_ + m0 + c * 4;
        float4 v = *(float4*)&Sp[idx];
        v.x = __expf(v.x - gm.x) * gi.x;
        v.y = __expf(v.y - gm.y) * gi.y;
        v.z = __expf(v.z - gm.z) * gi.z;
        v.w = __expf(v.w - gm.w) * gi.w;
        *(float4*)&Sp[idx] = v;              // prob fp32 output (in place)
        T[r][c * 4 + 0] = v.x;
        T[r][c * 4 + 1] = v.y;
        T[r][c * 4 + 2] = v.z;
        T[r][c * 4 + 3] = v.w;
    }
    __syncthreads();

    const int ml = t >> 2;        // m_local 0..63
    const int ns = t & 3;         // n segment (16 each)
    uint16_t* PtB = Pt + ((size_t)b * M_ + m0 + ml) * N_ + n0 + ns * 16;
    u16x8 s0, s1;
    #pragma unroll
    for (int jj = 0; jj < 8; ++jj) s0[jj] = f2bf(T[ns * 16 + jj][ml]);
    #pragma unroll
    for (int jj = 0; jj < 8; ++jj) s1[jj] = f2bf(T[ns * 16 + 8 + jj][ml]);
    *(u16x8*)&PtB[0] = s0;
    *(u16x8*)&PtB[8] = s1;
}

// ---------------------------------------------------------------------------
// Kernel 5 (fast path): mo fp32 -> bf16, same layout [B][DO][N].
// ---------------------------------------------------------------------------
__global__ __launch_bounds__(256) void k_moconv(const float* __restrict__ mo,
                                                uint16_t* __restrict__ mo16) {
    const size_t base = ((size_t)blockIdx.x * 256 + threadIdx.x) * 16;
    float4 v0 = *(const float4*)&mo[base + 0];
    float4 v1 = *(const float4*)&mo[base + 4];
    float4 v2 = *(const float4*)&mo[base + 8];
    float4 v3 = *(const float4*)&mo[base + 12];
    u16x8 o0, o1;
    o0[0] = f2bf(v0.x); o0[1] = f2bf(v0.y); o0[2] = f2bf(v0.z); o0[3] = f2bf(v0.w);
    o0[4] = f2bf(v1.x); o0[5] = f2bf(v1.y); o0[6] = f2bf(v1.z); o0[7] = f2bf(v1.w);
    o1[0] = f2bf(v2.x); o1[1] = f2bf(v2.y); o1[2] = f2bf(v2.z); o1[3] = f2bf(v2.w);
    o1[4] = f2bf(v3.x); o1[5] = f2bf(v3.y); o1[6] = f2bf(v3.z); o1[7] = f2bf(v3.w);
    *(u16x8*)&mo16[base + 0] = o0;
    *(u16x8*)&mo16[base + 8] = o1;
}

// ---------------------------------------------------------------------------
// Kernel 6 (fast path): PV via bf16 MFMA, split-K.
// partial[sk][b][d][m] = sum_{n in chunk sk} mo[b,d,n] * prob[b,n,m]
// Block tile 128(d) x 128(m) x BK=64, 4 waves (2x2), wave tile 64x64.
// LDS rows padded to 88 shorts (176 B): 16B-aligned, 2-way banks max.
// ---------------------------------------------------------------------------
__global__ __launch_bounds__(256) void k_pv_mfma(const uint16_t* __restrict__ mo16,
                                                 const uint16_t* __restrict__ Pt,
                                                 float* __restrict__ part) {
    __shared__ uint16_t Asm[128 * 88];   // [d_local][k], k-contiguous
    __shared__ uint16_t Psm[128 * 88];   // [m_local][k]
    const int m0 = blockIdx.x * 128;
    const int d0 = blockIdx.y * 128;
    const int b  = blockIdx.z >> 2;
    const int sk = blockIdx.z & 3;
    const int tid = threadIdx.x;

    const uint16_t* moB = mo16 + (size_t)b * DO_ * N_;
    const uint16_t* PtB = Pt   + (size_t)b * M_  * N_;

    const int srow = tid >> 3;   // 0..31 (+32*i): staging row
    const int sseg = tid & 7;    // 16B segment within 64-wide k row

    const int w  = tid >> 6;
    const int wd = w >> 1, wm = w & 1;
    const int l  = tid & 63;
    const int lr = l & 15;
    const int lg = l >> 4;       // 0..3

    f32x4 acc[4][4] = {};

    for (int n0 = sk * KCHUNK_; n0 < (sk + 1) * KCHUNK_; n0 += 64) {
        #pragma unroll
        for (int i = 0; i < 4; ++i) {
            int r = srow + i * 32;
            *(bf16x8*)&Asm[r * 88 + sseg * 8] =
                *(const bf16x8*)&moB[(size_t)(d0 + r) * N_ + n0 + sseg * 8];
            *(bf16x8*)&Psm[r * 88 + sseg * 8] =
                *(const bf16x8*)&PtB[(size_t)(m0 + r) * N_ + n0 + sseg * 8];
        }
        __syncthreads();
        #pragma unroll
        for (int kk = 0; kk < 64; kk += 32) {
            bf16x8 a[4], p[4];
            #pragma unroll
            for (int i = 0; i < 4; ++i)
                a[i] = *(const bf16x8*)&Asm[(wd * 64 + i * 16 + lr) * 88 + kk + lg * 8];
            #pragma unroll
            for (int j = 0; j < 4; ++j)
                p[j] = *(const bf16x8*)&Psm[(wm * 64 + j * 16 + lr) * 88 + kk + lg * 8];
            #pragma unroll
            for (int i = 0; i < 4; ++i)
                #pragma unroll
                for (int j = 0; j < 4; ++j)
                    acc[i][j] = __builtin_amdgcn_mfma_f32_16x16x32_bf16(
                        a[i], p[j], acc[i][j], 0, 0, 0);
        }
        __syncthreads();
    }

    float* pp = part + ((size_t)(sk * B_ + b) * DO_ + d0) * M_;
    #pragma unroll
    for (int i = 0; i < 4; ++i)
        #pragma unroll
        for (int j = 0; j < 4; ++j)
            #pragma unroll
            for (int r = 0; r < 4; ++r) {
                int d = wd * 64 + i * 16 + lg * 4 + r;   // C/D row (m89-verified)
                int m = wm * 64 + j * 16 + lr;           // C/D col = lane&15
                pp[(size_t)d * M_ + m0 + m] = acc[i][j][r];
            }
}

// ---------------------------------------------------------------------------
// Kernel 7 (fast path): sum the 4 split-K partials into out channels [0,DO).
// ---------------------------------------------------------------------------
__global__ __launch_bounds__(256) void k_pvreduce(const float* __restrict__ part,
                                                  float* __restrict__ out) {
    constexpr size_t OUTSZ = (size_t)B_ * DO_ * M_;
    const size_t i = (size_t)blockIdx.x * 256 + threadIdx.x;
    const size_t e = i * 4;
    float4 a = *(const float4*)&part[e];
    float4 b = *(const float4*)&part[OUTSZ + e];
    float4 c = *(const float4*)&part[2 * OUTSZ + e];
    float4 d = *(const float4*)&part[3 * OUTSZ + e];
    a.x += b.x + c.x + d.x;
    a.y += b.y + c.y + d.y;
    a.z += b.z + c.z + d.z;
    a.w += b.w + c.w + d.w;
    const int bb = (int)(e / ((size_t)DO_ * M_));
    const size_t rem = e % ((size_t)DO_ * M_);
    *(float4*)&out[(size_t)bb * 2 * DO_ * M_ + rem] = a;
}

// ---------------------------------------------------------------------------
// Fallback fp32 kernels (used when ws_size is too small for the MFMA path)
// ---------------------------------------------------------------------------
__global__ __launch_bounds__(256) void k_normalize(float* __restrict__ S,
                                                   const float* __restrict__ gmax,
                                                   const float* __restrict__ ginv) {
    const size_t total4 = (size_t)B_ * N_ * M_ / 4;
    for (size_t i = (size_t)blockIdx.x * 256 + threadIdx.x; i < total4;
         i += (size_t)gridDim.x * 256) {
        size_t e = i * 4;
        int b = (int)(e / ((size_t)N_ * M_));
        int m = (int)(e & (M_ - 1));
        float4 v = ((float4*)S)[i];
        float4 gm = *(const float4*)&gmax[b * M_ + m];
        float4 gi = *(const float4*)&ginv[b * M_ + m];
        v.x = __expf(v.x - gm.x) * gi.x;
        v.y = __expf(v.y - gm.y) * gi.y;
        v.z = __expf(v.z - gm.z) * gi.z;
        v.w = __expf(v.w - gm.w) * gi.w;
        ((float4*)S)[i] = v;
    }
}

__global__ __launch_bounds__(256) void k_pv(const float* __restrict__ mo,
                                            const float* __restrict__ P,
                                            float* __restrict__ out) {
    __shared__ float As[32][68];
    __shared__ float Ps[32][64];
    const int m0 = blockIdx.x * 64;
    const int d0 = blockIdx.y * 64;
    const int b  = blockIdx.z;
    const int tid = threadIdx.x;
    const int tx = tid & 15;
    const int ty = tid >> 4;

    const float* moB = mo + (size_t)b * DO_ * N_;
    const float* PB  = P  + (size_t)b * N_ * M_;

    float acc[4][4] = {};

    for (int n0 = 0; n0 < N_; n0 += 32) {
        #pragma unroll
        for (int t = 0; t < 8; ++t) {
            int e = tid + t * 256;
            int dd = e >> 5, nn = e & 31;
            As[nn][dd] = moB[(size_t)(d0 + dd) * N_ + n0 + nn];
        }
        #pragma unroll
        for (int t = 0; t < 8; ++t) {
            int e = tid + t * 256;
            int kk = e >> 6, mm = e & 63;
            Ps[kk][mm] = PB[(size_t)(n0 + kk) * M_ + m0 + mm];
        }
        __syncthreads();
        #pragma unroll
        for (int kk = 0; kk < 32; ++kk) {
            float a[4], p[4];
            #pragma unroll
            for (int i = 0; i < 4; ++i) a[i] = As[kk][ty * 4 + i];
            #pragma unroll
            for (int j = 0; j < 4; ++j) p[j] = Ps[kk][tx * 4 + j];
            #pragma unroll
            for (int i = 0; i < 4; ++i)
                #pragma unroll
                for (int j = 0; j < 4; ++j)
                    acc[i][j] = fmaf(a[i], p[j], acc[i][j]);
        }
        __syncthreads();
    }

    float* outB = out + (size_t)b * 2 * DO_ * M_;
    #pragma unroll
    for (int i = 0; i < 4; ++i) {
        float4 v = make_float4(acc[i][0], acc[i][1], acc[i][2], acc[i][3]);
        *(float4*)&outB[(size_t)(d0 + ty * 4 + i) * M_ + m0 + tx * 4] = v;
    }
}

// ---------------------------------------------------------------------------
// Kernel 8: copy query_out into channels [DO, 2*DO).
// ---------------------------------------------------------------------------
__global__ __launch_bounds__(256) void k_copyq(const float* __restrict__ q,
                                               float* __restrict__ out) {
    const size_t i = (size_t)blockIdx.x * 256 + threadIdx.x;
    const size_t e = i * 4;
    const int b = (int)(e / ((size_t)DO_ * M_));
    const size_t r = e % ((size_t)DO_ * M_);
    float4 v = *(const float4*)&q[e];
    *(float4*)&out[(size_t)b * 2 * DO_ * M_ + (size_t)DO_ * M_ + r] = v;
}

// ---------------------------------------------------------------------------
extern "C" void kernel_launch(void* const* d_in, const int* in_sizes, int n_in,
                              void* d_out, int out_size, void* d_ws, size_t ws_size,
                              hipStream_t stream) {
    const float* mi = (const float*)d_in[0];  // memory_in  [B,128,8192]
    const float* mo = (const float*)d_in[1];  // memory_out [B,512,8192]
    const float* qi = (const float*)d_in[2];  // query_in   [B,128,1024]
    const float* qo = (const float*)d_in[3];  // query_out  [B,512,1024]

    float* out  = (float*)d_out;                       // [B,1024,1024]
    float* prob = out + (size_t)B_ * 2 * DO_ * M_;     // [B,8192,1024]

    // workspace layout
    float* pmax = (float*)d_ws;                        // [B,32,M]
    float* psum = pmax + (size_t)B_ * NCHUNK_ * M_;    // [B,32,M]
    float* gmax = psum + (size_t)B_ * NCHUNK_ * M_;    // [B,M]
    float* ginv = gmax + (size_t)B_ * M_;              // [B,M]
    uint16_t* Pt   = (uint16_t*)(ginv + B_ * M_);      // [B,M,N] bf16 transposed prob
    uint16_t* mo16 = Pt + (size_t)B_ * M_ * N_;        // [B,DO,N] bf16
    float*    part = (float*)(mo16 + (size_t)B_ * DO_ * N_);  // [SPLITK,B,DO,M]
    const size_t need =
        (size_t)((char*)(part + (size_t)SPLITK_ * B_ * DO_ * M_) - (char*)d_ws);

    k_scores  <<<dim3(M_ / 64, N_ / 64, B_), 256, 0, stream>>>(mi, qi, prob);
    k_colstats<<<dim3(M_ / 256, NCHUNK_, B_), 256, 0, stream>>>(prob, pmax, psum);
    k_reduce  <<<dim3(B_ * M_ / 256), 256, 0, stream>>>(pmax, psum, gmax, ginv);

    if (ws_size >= need) {
        // fast MFMA path
        k_moconv     <<<dim3((B_ * DO_ * N_ / 16) / 256), 256, 0, stream>>>(mo, mo16);
        k_normalize_t<<<dim3(M_ / 64, N_ / 64, B_), 256, 0, stream>>>(prob, gmax, ginv, Pt);
        k_pv_mfma    <<<dim3(M_ / 128, DO_ / 128, B_ * SPLITK_), 256, 0, stream>>>(mo16, Pt, part);
        k_pvreduce   <<<dim3((B_ * DO_ * M_ / 4) / 256), 256, 0, stream>>>(part, out);
    } else {
        // fp32 fallback path
        k_normalize<<<dim3(2048), 256, 0, stream>>>(prob, gmax, ginv);
        k_pv       <<<dim3(M_ / 64, DO_ / 64, B_), 256, 0, stream>>>(mo, prob, out);
    }
    k_copyq<<<dim3((B_ * DO_ * M_ / 4) / 256), 256, 0, stream>>>(qo, out);
}

// Round 7
// 388.574 us; speedup vs baseline: 2.3626x; 1.2036x over previous
//
#include <hip/hip_runtime.h>
#include <math.h>
#include <stdint.h>

// Problem constants (B, D_e, D_o, T, H, W) = (4, 128, 512, 8, 32, 32)
constexpr int B_  = 4;
constexpr int DE_ = 128;
constexpr int DO_ = 512;
constexpr int N_  = 8192;   // T*H*W (memory keys)
constexpr int M_  = 1024;   // H*W   (query positions)
constexpr int NCHUNK_ = 32; // softmax N-chunks
constexpr int SPLITK_ = 4;  // k_pv split-K factor
constexpr int KCHUNK_ = N_ / SPLITK_;  // 2048

typedef __attribute__((ext_vector_type(8))) short bf16x8;
typedef __attribute__((ext_vector_type(8))) unsigned short u16x8;
typedef __attribute__((ext_vector_type(4))) float f32x4;

static __device__ __forceinline__ uint16_t f2bf(float f) {
    uint32_t u = __builtin_bit_cast(uint32_t, f);
    u += 0x7fffu + ((u >> 16) & 1u);   // round-to-nearest-even
    return (uint16_t)(u >> 16);
}

// ---------------------------------------------------------------------------
// Kernel 0 (fast path): transpose-convert [DE][ncols] fp32 -> [ncols][DE] bf16.
// Reads wave-coalesced along n (64 lanes x 4B contiguous per d-row); writes
// 16B per lane at 256B stride — the 4 dsegs of the block complete full lines.
// ---------------------------------------------------------------------------
__global__ __launch_bounds__(256) void k_tconv(const float* __restrict__ src,
                                               uint16_t* __restrict__ dst,
                                               int ncols) {
    const int n    = blockIdx.x * 64 + (threadIdx.x & 63);
    const int dseg = threadIdx.x >> 6;            // 0..3
    const int b    = blockIdx.y;
    const float* s = src + (size_t)b * DE_ * ncols + n;
    uint16_t*    d = dst + ((size_t)b * ncols + n) * DE_;
    #pragma unroll
    for (int db = 0; db < 4; ++db) {
        int d0 = db * 32 + dseg * 8;
        u16x8 o;
        #pragma unroll
        for (int q = 0; q < 8; ++q) o[q] = f2bf(s[(size_t)(d0 + q) * ncols]);
        *(u16x8*)&d[d0] = o;
    }
}

// ---------------------------------------------------------------------------
// Kernel 1a (fast path): S[b,n,m] = scale * sum_d mit[b,n,d] * qit[b,m,d]
// via bf16 MFMA. Structural clone of the validated k_pv_mfma: 128x128 tile,
// BK=64 (two K-steps cover DE=128), 4 waves (2x2), LDS rows 88 shorts.
// ---------------------------------------------------------------------------
__global__ __launch_bounds__(256) void k_scores_mfma(const uint16_t* __restrict__ mit,
                                                     const uint16_t* __restrict__ qit,
                                                     float* __restrict__ S) {
    __shared__ uint16_t Asm[128 * 88];   // [n_local][k]
    __shared__ uint16_t Bsm[128 * 88];   // [m_local][k]
    const int m0 = blockIdx.x * 128;
    const int n0 = blockIdx.y * 128;
    const int b  = blockIdx.z;
    const int tid = threadIdx.x;

    const uint16_t* A  = mit + (size_t)b * N_ * DE_;
    const uint16_t* Bq = qit + (size_t)b * M_ * DE_;

    const int srow = tid >> 3;   // 0..31 (+32*i)
    const int sseg = tid & 7;    // 16B segment within 64-wide k row

    const int w  = tid >> 6;
    const int wn = w >> 1, wm = w & 1;
    const int l  = tid & 63;
    const int lr = l & 15;
    const int lg = l >> 4;

    f32x4 acc[4][4] = {};

    for (int k0 = 0; k0 < DE_; k0 += 64) {
        #pragma unroll
        for (int i = 0; i < 4; ++i) {
            int r = srow + i * 32;
            *(bf16x8*)&Asm[r * 88 + sseg * 8] =
                *(const bf16x8*)&A[(size_t)(n0 + r) * DE_ + k0 + sseg * 8];
            *(bf16x8*)&Bsm[r * 88 + sseg * 8] =
                *(const bf16x8*)&Bq[(size_t)(m0 + r) * DE_ + k0 + sseg * 8];
        }
        __syncthreads();
        #pragma unroll
        for (int kk = 0; kk < 64; kk += 32) {
            bf16x8 a[4], p[4];
            #pragma unroll
            for (int i = 0; i < 4; ++i)
                a[i] = *(const bf16x8*)&Asm[(wn * 64 + i * 16 + lr) * 88 + kk + lg * 8];
            #pragma unroll
            for (int j = 0; j < 4; ++j)
                p[j] = *(const bf16x8*)&Bsm[(wm * 64 + j * 16 + lr) * 88 + kk + lg * 8];
            #pragma unroll
            for (int i = 0; i < 4; ++i)
                #pragma unroll
                for (int j = 0; j < 4; ++j)
                    acc[i][j] = __builtin_amdgcn_mfma_f32_16x16x32_bf16(
                        a[i], p[j], acc[i][j], 0, 0, 0);
        }
        __syncthreads();
    }

    const float scale = 0.08838834764831845f;  // 1/sqrt(128)
    float* Sp = S + (size_t)b * N_ * M_;
    #pragma unroll
    for (int i = 0; i < 4; ++i)
        #pragma unroll
        for (int j = 0; j < 4; ++j)
            #pragma unroll
            for (int r = 0; r < 4; ++r) {
                int n = n0 + wn * 64 + i * 16 + lg * 4 + r;  // C/D row
                int m = m0 + wm * 64 + j * 16 + lr;          // C/D col = lane&15
                Sp[(size_t)n * M_ + m] = acc[i][j][r] * scale;
            }
}

// ---------------------------------------------------------------------------
// Kernel 1b (fallback): fp32 scores.
// ---------------------------------------------------------------------------
__global__ __launch_bounds__(256) void k_scores(const float* __restrict__ mi,
                                                const float* __restrict__ qi,
                                                float* __restrict__ S) {
    __shared__ float As[32][64];
    __shared__ float Bs[32][64];
    const int m0 = blockIdx.x * 64;
    const int n0 = blockIdx.y * 64;
    const int b  = blockIdx.z;
    const int tid = threadIdx.x;
    const int tx = tid & 15;
    const int ty = tid >> 4;

    const float* miB = mi + (size_t)b * DE_ * N_;
    const float* qiB = qi + (size_t)b * DE_ * M_;

    float acc[4][4] = {};

    for (int k0 = 0; k0 < DE_; k0 += 32) {
        #pragma unroll
        for (int t = 0; t < 8; ++t) {
            int e = tid + t * 256;
            int kk = e >> 6, nn = e & 63;
            As[kk][nn] = miB[(size_t)(k0 + kk) * N_ + n0 + nn];
            Bs[kk][nn] = qiB[(size_t)(k0 + kk) * M_ + m0 + nn];
        }
        __syncthreads();
        #pragma unroll
        for (int kk = 0; kk < 32; ++kk) {
            float a[4], p[4];
            #pragma unroll
            for (int i = 0; i < 4; ++i) a[i] = As[kk][ty * 4 + i];
            #pragma unroll
            for (int j = 0; j < 4; ++j) p[j] = Bs[kk][tx * 4 + j];
            #pragma unroll
            for (int i = 0; i < 4; ++i)
                #pragma unroll
                for (int j = 0; j < 4; ++j)
                    acc[i][j] = fmaf(a[i], p[j], acc[i][j]);
        }
        __syncthreads();
    }

    const float scale = 0.08838834764831845f;  // 1/sqrt(128)
    float* Sp = S + (size_t)b * N_ * M_;
    #pragma unroll
    for (int i = 0; i < 4; ++i) {
        float4 v = make_float4(acc[i][0] * scale, acc[i][1] * scale,
                               acc[i][2] * scale, acc[i][3] * scale);
        *(float4*)&Sp[(size_t)(n0 + ty * 4 + i) * M_ + m0 + tx * 4] = v;
    }
}

// ---------------------------------------------------------------------------
// Kernel 2: per-(b,m) column partial softmax stats over a 256-row N chunk.
// ---------------------------------------------------------------------------
__global__ __launch_bounds__(256) void k_colstats(const float* __restrict__ S,
                                                  float* __restrict__ pmax,
                                                  float* __restrict__ psum) {
    const int m = blockIdx.x * 256 + threadIdx.x;
    const int c = blockIdx.y;
    const int b = blockIdx.z;
    const float* Sp = S + (size_t)b * N_ * M_ + (size_t)c * 256 * M_ + m;
    float mx = -INFINITY, sm = 0.f;
    for (int n = 0; n < 256; ++n) {
        float x = Sp[(size_t)n * M_];
        float mnew = fmaxf(mx, x);
        sm = sm * __expf(mx - mnew) + __expf(x - mnew);
        mx = mnew;
    }
    size_t idx = ((size_t)b * NCHUNK_ + c) * M_ + m;
    pmax[idx] = mx;
    psum[idx] = sm;
}

// ---------------------------------------------------------------------------
// Kernel 3: combine chunk partials -> gmax, 1/sum.
// ---------------------------------------------------------------------------
__global__ __launch_bounds__(256) void k_reduce(const float* __restrict__ pmax,
                                                const float* __restrict__ psum,
                                                float* __restrict__ gmax,
                                                float* __restrict__ ginv) {
    const int g = blockIdx.x * 256 + threadIdx.x;
    const int b = g >> 10;
    const int m = g & (M_ - 1);
    float pm[NCHUNK_];
    float mx = -INFINITY;
    #pragma unroll
    for (int c = 0; c < NCHUNK_; ++c) {
        pm[c] = pmax[((size_t)b * NCHUNK_ + c) * M_ + m];
        mx = fmaxf(mx, pm[c]);
    }
    float sm = 0.f;
    #pragma unroll
    for (int c = 0; c < NCHUNK_; ++c) {
        sm += psum[((size_t)b * NCHUNK_ + c) * M_ + m] * __expf(pm[c] - mx);
    }
    gmax[g] = mx;
    ginv[g] = 1.0f / sm;
}

// ---------------------------------------------------------------------------
// Kernel 4 (fast path): normalize in place AND emit transposed bf16 copy
// Pt[b][m][n] for the MFMA PV kernel. 64(n) x 64(m) tile via LDS.
// ---------------------------------------------------------------------------
__global__ __launch_bounds__(256) void k_normalize_t(float* __restrict__ S,
                                                     const float* __restrict__ gmax,
                                                     const float* __restrict__ ginv,
                                                     uint16_t* __restrict__ Pt) {
    __shared__ float T[64][65];   // [n_local][m_local], stride 65 (bank-safe)
    const int m0 = blockIdx.x * 64;
    const int n0 = blockIdx.y * 64;
    const int b  = blockIdx.z;
    const int t  = threadIdx.x;
    const int c  = t & 15;        // m quad
    const int rr = t >> 4;        // 0..15

    float4 gm = *(const float4*)&gmax[b * M_ + m0 + c * 4];
    float4 gi = *(const float4*)&ginv[b * M_ + m0 + c * 4];
    float* Sp = S + (size_t)b * N_ * M_;

    #pragma unroll
    for (int it = 0; it < 4; ++it) {
        int r = rr + it * 16;
        size_t idx = (size_t)(n0 + r) * M_ + m0 + c * 4;
        float4 v = *(float4*)&Sp[idx];
        v.x = __expf(v.x - gm.x) * gi.x;
        v.y = __expf(v.y - gm.y) * gi.y;
        v.z = __expf(v.z - gm.z) * gi.z;
        v.w = __expf(v.w - gm.w) * gi.w;
        *(float4*)&Sp[idx] = v;              // prob fp32 output (in place)
        T[r][c * 4 + 0] = v.x;
        T[r][c * 4 + 1] = v.y;
        T[r][c * 4 + 2] = v.z;
        T[r][c * 4 + 3] = v.w;
    }
    __syncthreads();

    const int ml = t >> 2;        // m_local 0..63
    const int ns = t & 3;         // n segment (16 each)
    uint16_t* PtB = Pt + ((size_t)b * M_ + m0 + ml) * N_ + n0 + ns * 16;
    u16x8 s0, s1;
    #pragma unroll
    for (int jj = 0; jj < 8; ++jj) s0[jj] = f2bf(T[ns * 16 + jj][ml]);
    #pragma unroll
    for (int jj = 0; jj < 8; ++jj) s1[jj] = f2bf(T[ns * 16 + 8 + jj][ml]);
    *(u16x8*)&PtB[0] = s0;
    *(u16x8*)&PtB[8] = s1;
}

// ---------------------------------------------------------------------------
// Kernel 5 (fast path): mo fp32 -> bf16, same layout [B][DO][N].
// ---------------------------------------------------------------------------
__global__ __launch_bounds__(256) void k_moconv(const float* __restrict__ mo,
                                                uint16_t* __restrict__ mo16) {
    const size_t base = ((size_t)blockIdx.x * 256 + threadIdx.x) * 16;
    float4 v0 = *(const float4*)&mo[base + 0];
    float4 v1 = *(const float4*)&mo[base + 4];
    float4 v2 = *(const float4*)&mo[base + 8];
    float4 v3 = *(const float4*)&mo[base + 12];
    u16x8 o0, o1;
    o0[0] = f2bf(v0.x); o0[1] = f2bf(v0.y); o0[2] = f2bf(v0.z); o0[3] = f2bf(v0.w);
    o0[4] = f2bf(v1.x); o0[5] = f2bf(v1.y); o0[6] = f2bf(v1.z); o0[7] = f2bf(v1.w);
    o1[0] = f2bf(v2.x); o1[1] = f2bf(v2.y); o1[2] = f2bf(v2.z); o1[3] = f2bf(v2.w);
    o1[4] = f2bf(v3.x); o1[5] = f2bf(v3.y); o1[6] = f2bf(v3.z); o1[7] = f2bf(v3.w);
    *(u16x8*)&mo16[base + 0] = o0;
    *(u16x8*)&mo16[base + 8] = o1;
}

// ---------------------------------------------------------------------------
// Kernel 6 (fast path): PV via bf16 MFMA, split-K.
// ---------------------------------------------------------------------------
__global__ __launch_bounds__(256) void k_pv_mfma(const uint16_t* __restrict__ mo16,
                                                 const uint16_t* __restrict__ Pt,
                                                 float* __restrict__ part) {
    __shared__ uint16_t Asm[128 * 88];   // [d_local][k], k-contiguous
    __shared__ uint16_t Psm[128 * 88];   // [m_local][k]
    const int m0 = blockIdx.x * 128;
    const int d0 = blockIdx.y * 128;
    const int b  = blockIdx.z >> 2;
    const int sk = blockIdx.z & 3;
    const int tid = threadIdx.x;

    const uint16_t* moB = mo16 + (size_t)b * DO_ * N_;
    const uint16_t* PtB = Pt   + (size_t)b * M_  * N_;

    const int srow = tid >> 3;   // 0..31 (+32*i): staging row
    const int sseg = tid & 7;    // 16B segment within 64-wide k row

    const int w  = tid >> 6;
    const int wd = w >> 1, wm = w & 1;
    const int l  = tid & 63;
    const int lr = l & 15;
    const int lg = l >> 4;       // 0..3

    f32x4 acc[4][4] = {};

    for (int n0 = sk * KCHUNK_; n0 < (sk + 1) * KCHUNK_; n0 += 64) {
        #pragma unroll
        for (int i = 0; i < 4; ++i) {
            int r = srow + i * 32;
            *(bf16x8*)&Asm[r * 88 + sseg * 8] =
                *(const bf16x8*)&moB[(size_t)(d0 + r) * N_ + n0 + sseg * 8];
            *(bf16x8*)&Psm[r * 88 + sseg * 8] =
                *(const bf16x8*)&PtB[(size_t)(m0 + r) * N_ + n0 + sseg * 8];
        }
        __syncthreads();
        #pragma unroll
        for (int kk = 0; kk < 64; kk += 32) {
            bf16x8 a[4], p[4];
            #pragma unroll
            for (int i = 0; i < 4; ++i)
                a[i] = *(const bf16x8*)&Asm[(wd * 64 + i * 16 + lr) * 88 + kk + lg * 8];
            #pragma unroll
            for (int j = 0; j < 4; ++j)
                p[j] = *(const bf16x8*)&Psm[(wm * 64 + j * 16 + lr) * 88 + kk + lg * 8];
            #pragma unroll
            for (int i = 0; i < 4; ++i)
                #pragma unroll
                for (int j = 0; j < 4; ++j)
                    acc[i][j] = __builtin_amdgcn_mfma_f32_16x16x32_bf16(
                        a[i], p[j], acc[i][j], 0, 0, 0);
        }
        __syncthreads();
    }

    float* pp = part + ((size_t)(sk * B_ + b) * DO_ + d0) * M_;
    #pragma unroll
    for (int i = 0; i < 4; ++i)
        #pragma unroll
        for (int j = 0; j < 4; ++j)
            #pragma unroll
            for (int r = 0; r < 4; ++r) {
                int d = wd * 64 + i * 16 + lg * 4 + r;   // C/D row (m89-verified)
                int m = wm * 64 + j * 16 + lr;           // C/D col = lane&15
                pp[(size_t)d * M_ + m0 + m] = acc[i][j][r];
            }
}

// ---------------------------------------------------------------------------
// Kernel 7 (fast path): sum the 4 split-K partials into out channels [0,DO).
// ---------------------------------------------------------------------------
__global__ __launch_bounds__(256) void k_pvreduce(const float* __restrict__ part,
                                                  float* __restrict__ out) {
    constexpr size_t OUTSZ = (size_t)B_ * DO_ * M_;
    const size_t i = (size_t)blockIdx.x * 256 + threadIdx.x;
    const size_t e = i * 4;
    float4 a = *(const float4*)&part[e];
    float4 b = *(const float4*)&part[OUTSZ + e];
    float4 c = *(const float4*)&part[2 * OUTSZ + e];
    float4 d = *(const float4*)&part[3 * OUTSZ + e];
    a.x += b.x + c.x + d.x;
    a.y += b.y + c.y + d.y;
    a.z += b.z + c.z + d.z;
    a.w += b.w + c.w + d.w;
    const int bb = (int)(e / ((size_t)DO_ * M_));
    const size_t rem = e % ((size_t)DO_ * M_);
    *(float4*)&out[(size_t)bb * 2 * DO_ * M_ + rem] = a;
}

// ---------------------------------------------------------------------------
// Fallback fp32 kernels (used when ws_size is too small for the MFMA path)
// ---------------------------------------------------------------------------
__global__ __launch_bounds__(256) void k_normalize(float* __restrict__ S,
                                                   const float* __restrict__ gmax,
                                                   const float* __restrict__ ginv) {
    const size_t total4 = (size_t)B_ * N_ * M_ / 4;
    for (size_t i = (size_t)blockIdx.x * 256 + threadIdx.x; i < total4;
         i += (size_t)gridDim.x * 256) {
        size_t e = i * 4;
        int b = (int)(e / ((size_t)N_ * M_));
        int m = (int)(e & (M_ - 1));
        float4 v = ((float4*)S)[i];
        float4 gm = *(const float4*)&gmax[b * M_ + m];
        float4 gi = *(const float4*)&ginv[b * M_ + m];
        v.x = __expf(v.x - gm.x) * gi.x;
        v.y = __expf(v.y - gm.y) * gi.y;
        v.z = __expf(v.z - gm.z) * gi.z;
        v.w = __expf(v.w - gm.w) * gi.w;
        ((float4*)S)[i] = v;
    }
}

__global__ __launch_bounds__(256) void k_pv(const float* __restrict__ mo,
                                            const float* __restrict__ P,
                                            float* __restrict__ out) {
    __shared__ float As[32][68];
    __shared__ float Ps[32][64];
    const int m0 = blockIdx.x * 64;
    const int d0 = blockIdx.y * 64;
    const int b  = blockIdx.z;
    const int tid = threadIdx.x;
    const int tx = tid & 15;
    const int ty = tid >> 4;

    const float* moB = mo + (size_t)b * DO_ * N_;
    const float* PB  = P  + (size_t)b * N_ * M_;

    float acc[4][4] = {};

    for (int n0 = 0; n0 < N_; n0 += 32) {
        #pragma unroll
        for (int t = 0; t < 8; ++t) {
            int e = tid + t * 256;
            int dd = e >> 5, nn = e & 31;
            As[nn][dd] = moB[(size_t)(d0 + dd) * N_ + n0 + nn];
        }
        #pragma unroll
        for (int t = 0; t < 8; ++t) {
            int e = tid + t * 256;
            int kk = e >> 6, mm = e & 63;
            Ps[kk][mm] = PB[(size_t)(n0 + kk) * M_ + m0 + mm];
        }
        __syncthreads();
        #pragma unroll
        for (int kk = 0; kk < 32; ++kk) {
            float a[4], p[4];
            #pragma unroll
            for (int i = 0; i < 4; ++i) a[i] = As[kk][ty * 4 + i];
            #pragma unroll
            for (int j = 0; j < 4; ++j) p[j] = Ps[kk][tx * 4 + j];
            #pragma unroll
            for (int i = 0; i < 4; ++i)
                #pragma unroll
                for (int j = 0; j < 4; ++j)
                    acc[i][j] = fmaf(a[i], p[j], acc[i][j]);
        }
        __syncthreads();
    }

    float* outB = out + (size_t)b * 2 * DO_ * M_;
    #pragma unroll
    for (int i = 0; i < 4; ++i) {
        float4 v = make_float4(acc[i][0], acc[i][1], acc[i][2], acc[i][3]);
        *(float4*)&outB[(size_t)(d0 + ty * 4 + i) * M_ + m0 + tx * 4] = v;
    }
}

// ---------------------------------------------------------------------------
// Kernel 8: copy query_out into channels [DO, 2*DO).
// ---------------------------------------------------------------------------
__global__ __launch_bounds__(256) void k_copyq(const float* __restrict__ q,
                                               float* __restrict__ out) {
    const size_t i = (size_t)blockIdx.x * 256 + threadIdx.x;
    const size_t e = i * 4;
    const int b = (int)(e / ((size_t)DO_ * M_));
    const size_t r = e % ((size_t)DO_ * M_);
    float4 v = *(const float4*)&q[e];
    *(float4*)&out[(size_t)b * 2 * DO_ * M_ + (size_t)DO_ * M_ + r] = v;
}

// ---------------------------------------------------------------------------
extern "C" void kernel_launch(void* const* d_in, const int* in_sizes, int n_in,
                              void* d_out, int out_size, void* d_ws, size_t ws_size,
                              hipStream_t stream) {
    const float* mi = (const float*)d_in[0];  // memory_in  [B,128,8192]
    const float* mo = (const float*)d_in[1];  // memory_out [B,512,8192]
    const float* qi = (const float*)d_in[2];  // query_in   [B,128,1024]
    const float* qo = (const float*)d_in[3];  // query_out  [B,512,1024]

    float* out  = (float*)d_out;                       // [B,1024,1024]
    float* prob = out + (size_t)B_ * 2 * DO_ * M_;     // [B,8192,1024]

    // workspace layout
    float* pmax = (float*)d_ws;                        // [B,32,M]
    float* psum = pmax + (size_t)B_ * NCHUNK_ * M_;    // [B,32,M]
    float* gmax = psum + (size_t)B_ * NCHUNK_ * M_;    // [B,M]
    float* ginv = gmax + (size_t)B_ * M_;              // [B,M]
    uint16_t* Pt   = (uint16_t*)(ginv + B_ * M_);      // [B,M,N] bf16 transposed prob
    uint16_t* mo16 = Pt + (size_t)B_ * M_ * N_;        // [B,DO,N] bf16
    float*    part = (float*)(mo16 + (size_t)B_ * DO_ * N_);  // [SPLITK,B,DO,M]
    uint16_t* mit  = (uint16_t*)(part + (size_t)SPLITK_ * B_ * DO_ * M_); // [B,N,DE] bf16
    uint16_t* qit  = mit + (size_t)B_ * N_ * DE_;      // [B,M,DE] bf16
    const size_t need_fast =
        (size_t)((char*)mit - (char*)d_ws);            // PV-MFMA tier
    const size_t need_full =
        (size_t)((char*)(qit + (size_t)B_ * M_ * DE_) - (char*)d_ws);  // + scores-MFMA tier

    if (ws_size >= need_full) {
        // MFMA scores: transpose-convert operands, then 128x128 MFMA tiles
        k_tconv      <<<dim3(N_ / 64, B_), 256, 0, stream>>>(mi, mit, N_);
        k_tconv      <<<dim3(M_ / 64, B_), 256, 0, stream>>>(qi, qit, M_);
        k_scores_mfma<<<dim3(M_ / 128, N_ / 128, B_), 256, 0, stream>>>(mit, qit, prob);
    } else {
        k_scores<<<dim3(M_ / 64, N_ / 64, B_), 256, 0, stream>>>(mi, qi, prob);
    }

    k_colstats<<<dim3(M_ / 256, NCHUNK_, B_), 256, 0, stream>>>(prob, pmax, psum);
    k_reduce  <<<dim3(B_ * M_ / 256), 256, 0, stream>>>(pmax, psum, gmax, ginv);

    if (ws_size >= need_fast) {
        // fast MFMA PV path
        k_moconv     <<<dim3((B_ * DO_ * N_ / 16) / 256), 256, 0, stream>>>(mo, mo16);
        k_normalize_t<<<dim3(M_ / 64, N_ / 64, B_), 256, 0, stream>>>(prob, gmax, ginv, Pt);
        k_pv_mfma    <<<dim3(M_ / 128, DO_ / 128, B_ * SPLITK_), 256, 0, stream>>>(mo16, Pt, part);
        k_pvreduce   <<<dim3((B_ * DO_ * M_ / 4) / 256), 256, 0, stream>>>(part, out);
    } else {
        // fp32 fallback path
        k_normalize<<<dim3(2048), 256, 0, stream>>>(prob, gmax, ginv);
        k_pv       <<<dim3(M_ / 64, DO_ / 64, B_), 256, 0, stream>>>(mo, prob, out);
    }
    k_copyq<<<dim3((B_ * DO_ * M_ / 4) / 256), 256, 0, stream>>>(qo, out);
}

// Round 9
// 375.673 us; speedup vs baseline: 2.4438x; 1.0343x over previous
//
#include <hip/hip_runtime.h>
#include <math.h>
#include <stdint.h>

// Problem constants (B, D_e, D_o, T, H, W) = (4, 128, 512, 8, 32, 32)
constexpr int B_  = 4;
constexpr int DE_ = 128;
constexpr int DO_ = 512;
constexpr int N_  = 8192;   // T*H*W (memory keys)
constexpr int M_  = 1024;   // H*W   (query positions)
constexpr int NCHUNK_ = 32; // fp32-fallback softmax N-chunks
constexpr int NT_  = 64;    // stats chunks = N/128 tiles
constexpr int SPLITK_ = 4;  // k_pv split-K factor
constexpr int KCHUNK_ = N_ / SPLITK_;  // 2048

typedef __attribute__((ext_vector_type(8))) short bf16x8;
typedef __attribute__((ext_vector_type(8))) unsigned short u16x8;
typedef __attribute__((ext_vector_type(4))) unsigned short u16x4;
typedef __attribute__((ext_vector_type(4))) float f32x4;

static __device__ __forceinline__ uint16_t f2bf(float f) {
    uint32_t u = __builtin_bit_cast(uint32_t, f);
    u += 0x7fffu + ((u >> 16) & 1u);   // round-to-nearest-even
    return (uint16_t)(u >> 16);
}

// ---------------------------------------------------------------------------
// Kernel 0 (fast path): transpose-convert [DE][ncols] fp32 -> [ncols][DE] bf16.
// ---------------------------------------------------------------------------
__global__ __launch_bounds__(256) void k_tconv(const float* __restrict__ src,
                                               uint16_t* __restrict__ dst,
                                               int ncols) {
    const int n    = blockIdx.x * 64 + (threadIdx.x & 63);
    const int dseg = threadIdx.x >> 6;            // 0..3
    const int b    = blockIdx.y;
    const float* s = src + (size_t)b * DE_ * ncols + n;
    uint16_t*    d = dst + ((size_t)b * ncols + n) * DE_;
    #pragma unroll
    for (int db = 0; db < 4; ++db) {
        int d0 = db * 32 + dseg * 8;
        u16x8 o;
        #pragma unroll
        for (int q = 0; q < 8; ++q) o[q] = f2bf(s[(size_t)(d0 + q) * ncols]);
        *(u16x8*)&d[d0] = o;
    }
}

// ---------------------------------------------------------------------------
// Shared MFMA core for the two scores passes: computes the 128x128 tile
// acc[i][j] for block (m0 = bx*128, n0 = by*128, b = bz).
// ---------------------------------------------------------------------------
#define SCORES_MFMA_CORE(ASMV, BSMV)                                           \
    const int m0 = blockIdx.x * 128;                                           \
    const int n0 = blockIdx.y * 128;                                           \
    const int b  = blockIdx.z;                                                 \
    const int tid = threadIdx.x;                                               \
    const uint16_t* A  = mit + (size_t)b * N_ * DE_;                           \
    const uint16_t* Bq = qit + (size_t)b * M_ * DE_;                           \
    const int srow = tid >> 3;                                                 \
    const int sseg = tid & 7;                                                  \
    const int w  = tid >> 6;                                                   \
    const int wn = w >> 1, wm = w & 1;                                         \
    const int l  = tid & 63;                                                   \
    const int lr = l & 15;                                                     \
    const int lg = l >> 4;                                                     \
    f32x4 acc[4][4] = {};                                                      \
    for (int k0 = 0; k0 < DE_; k0 += 64) {                                     \
        _Pragma("unroll")                                                      \
        for (int i = 0; i < 4; ++i) {                                          \
            int r = srow + i * 32;                                             \
            *(bf16x8*)&ASMV[r * 88 + sseg * 8] =                               \
                *(const bf16x8*)&A[(size_t)(n0 + r) * DE_ + k0 + sseg * 8];    \
            *(bf16x8*)&BSMV[r * 88 + sseg * 8] =                               \
                *(const bf16x8*)&Bq[(size_t)(m0 + r) * DE_ + k0 + sseg * 8];   \
        }                                                                      \
        __syncthreads();                                                       \
        _Pragma("unroll")                                                      \
        for (int kk = 0; kk < 64; kk += 32) {                                  \
            bf16x8 a[4], p[4];                                                 \
            _Pragma("unroll")                                                  \
            for (int i = 0; i < 4; ++i)                                        \
                a[i] = *(const bf16x8*)&ASMV[(wn*64 + i*16 + lr)*88 + kk + lg*8]; \
            _Pragma("unroll")                                                  \
            for (int j = 0; j < 4; ++j)                                        \
                p[j] = *(const bf16x8*)&BSMV[(wm*64 + j*16 + lr)*88 + kk + lg*8]; \
            _Pragma("unroll")                                                  \
            for (int i = 0; i < 4; ++i)                                        \
                _Pragma("unroll")                                              \
                for (int j = 0; j < 4; ++j)                                    \
                    acc[i][j] = __builtin_amdgcn_mfma_f32_16x16x32_bf16(       \
                        a[i], p[j], acc[i][j], 0, 0, 0);                       \
        }                                                                      \
        __syncthreads();                                                       \
    }

// ---------------------------------------------------------------------------
// Kernel 1a (fast path, pass 1): per-tile column softmax stats, NO S write.
// Column m covers 128 n-rows of this tile: lane-local 16 values per j,
// shfl over lg (4 lanes), LDS combine across the two wn waves.
// ---------------------------------------------------------------------------
__global__ __launch_bounds__(256) void k_stats_mfma(const uint16_t* __restrict__ mit,
                                                    const uint16_t* __restrict__ qit,
                                                    float* __restrict__ pmax2,
                                                    float* __restrict__ psum2) {
    __shared__ uint16_t Asm[128 * 88];
    __shared__ uint16_t Bsm[128 * 88];
    __shared__ float wmx[2][128];
    __shared__ float wsm[2][128];

    SCORES_MFMA_CORE(Asm, Bsm)

    const float scale = 0.08838834764831845f;  // 1/sqrt(128)
    #pragma unroll
    for (int j = 0; j < 4; ++j) {
        float mx = -INFINITY;
        #pragma unroll
        for (int i = 0; i < 4; ++i)
            #pragma unroll
            for (int r = 0; r < 4; ++r)
                mx = fmaxf(mx, acc[i][j][r] * scale);
        mx = fmaxf(mx, __shfl_xor(mx, 16));
        mx = fmaxf(mx, __shfl_xor(mx, 32));
        float sm = 0.f;
        #pragma unroll
        for (int i = 0; i < 4; ++i)
            #pragma unroll
            for (int r = 0; r < 4; ++r)
                sm += __expf(acc[i][j][r] * scale - mx);
        sm += __shfl_xor(sm, 16);
        sm += __shfl_xor(sm, 32);
        if (lg == 0) {
            int col = wm * 64 + j * 16 + lr;
            wmx[wn][col] = mx;
            wsm[wn][col] = sm;
        }
    }
    __syncthreads();
    if (tid < 128) {
        float ma = wmx[0][tid], mb = wmx[1][tid];
        float mx = fmaxf(ma, mb);
        float sm = wsm[0][tid] * __expf(ma - mx) + wsm[1][tid] * __expf(mb - mx);
        size_t o = ((size_t)b * NT_ + blockIdx.y) * M_ + m0 + tid;
        pmax2[o] = mx;
        psum2[o] = sm;
    }
}

// ---------------------------------------------------------------------------
// Kernel 2 (fast path): online-combine the 64 chunk stats -> gmax, 1/sum.
// ---------------------------------------------------------------------------
__global__ __launch_bounds__(256) void k_reduce2(const float* __restrict__ pmax2,
                                                 const float* __restrict__ psum2,
                                                 float* __restrict__ gmax,
                                                 float* __restrict__ ginv) {
    const int g = blockIdx.x * 256 + threadIdx.x;  // b*M + m
    const int b = g >> 10;
    const int m = g & (M_ - 1);
    float mx = -INFINITY, sm = 0.f;
    for (int c = 0; c < NT_; ++c) {
        size_t idx = ((size_t)b * NT_ + c) * M_ + m;
        float pm = pmax2[idx];
        float ps = psum2[idx];
        float mnew = fmaxf(mx, pm);
        sm = sm * __expf(mx - mnew) + ps * __expf(pm - mnew);
        mx = mnew;
    }
    gmax[g] = mx;
    ginv[g] = 1.0f / sm;
}

// ---------------------------------------------------------------------------
// Kernel 1b (fast path, pass 2): recompute tile (bit-identical), write
// normalized prob fp32 [n][m] AND transposed bf16 Pt [m][n] directly.
// ---------------------------------------------------------------------------
__global__ __launch_bounds__(256) void k_prob_mfma(const uint16_t* __restrict__ mit,
                                                   const uint16_t* __restrict__ qit,
                                                   const float* __restrict__ gmax,
                                                   const float* __restrict__ ginv,
                                                   float* __restrict__ S,
                                                   uint16_t* __restrict__ Pt) {
    __shared__ uint16_t Asm[128 * 88];
    __shared__ uint16_t Bsm[128 * 88];

    SCORES_MFMA_CORE(Asm, Bsm)

    const float scale = 0.08838834764831845f;
    float gm[4], gi[4];
    #pragma unroll
    for (int j = 0; j < 4; ++j) {
        int m = m0 + wm * 64 + j * 16 + lr;
        gm[j] = gmax[b * M_ + m];
        gi[j] = ginv[b * M_ + m];
    }
    float* Sp = S + (size_t)b * N_ * M_;
    uint16_t* Ptp = Pt + (size_t)b * M_ * N_;
    #pragma unroll
    for (int i = 0; i < 4; ++i)
        #pragma unroll
        for (int j = 0; j < 4; ++j) {
            float p[4];
            #pragma unroll
            for (int r = 0; r < 4; ++r)
                p[r] = __expf(acc[i][j][r] * scale - gm[j]) * gi[j];
            const int n = n0 + wn * 64 + i * 16 + lg * 4;     // n..n+3
            const int m = m0 + wm * 64 + j * 16 + lr;
            #pragma unroll
            for (int r = 0; r < 4; ++r)
                Sp[(size_t)(n + r) * M_ + m] = p[r];          // prob fp32
            u16x4 o;
            #pragma unroll
            for (int r = 0; r < 4; ++r) o[r] = f2bf(p[r]);
            *(u16x4*)&Ptp[(size_t)m * N_ + n] = o;            // Pt bf16 (8B)
        }
}

// ---------------------------------------------------------------------------
// Kernel 5 (fast path): mo fp32 -> bf16, same layout [B][DO][N].
// ---------------------------------------------------------------------------
__global__ __launch_bounds__(256) void k_moconv(const float* __restrict__ mo,
                                                uint16_t* __restrict__ mo16) {
    const size_t base = ((size_t)blockIdx.x * 256 + threadIdx.x) * 16;
    float4 v0 = *(const float4*)&mo[base + 0];
    float4 v1 = *(const float4*)&mo[base + 4];
    float4 v2 = *(const float4*)&mo[base + 8];
    float4 v3 = *(const float4*)&mo[base + 12];
    u16x8 o0, o1;
    o0[0] = f2bf(v0.x); o0[1] = f2bf(v0.y); o0[2] = f2bf(v0.z); o0[3] = f2bf(v0.w);
    o0[4] = f2bf(v1.x); o0[5] = f2bf(v1.y); o0[6] = f2bf(v1.z); o0[7] = f2bf(v1.w);
    o1[0] = f2bf(v2.x); o1[1] = f2bf(v2.y); o1[2] = f2bf(v2.z); o1[3] = f2bf(v2.w);
    o1[4] = f2bf(v3.x); o1[5] = f2bf(v3.y); o1[6] = f2bf(v3.z); o1[7] = f2bf(v3.w);
    *(u16x8*)&mo16[base + 0] = o0;
    *(u16x8*)&mo16[base + 8] = o1;
}

// ---------------------------------------------------------------------------
// Kernel 6 (fast path): PV via bf16 MFMA, split-K. (validated, unchanged)
// ---------------------------------------------------------------------------
__global__ __launch_bounds__(256) void k_pv_mfma(const uint16_t* __restrict__ mo16,
                                                 const uint16_t* __restrict__ Pt,
                                                 float* __restrict__ part) {
    __shared__ uint16_t Asm[128 * 88];   // [d_local][k], k-contiguous
    __shared__ uint16_t Psm[128 * 88];   // [m_local][k]
    const int m0 = blockIdx.x * 128;
    const int d0 = blockIdx.y * 128;
    const int b  = blockIdx.z >> 2;
    const int sk = blockIdx.z & 3;
    const int tid = threadIdx.x;

    const uint16_t* moB = mo16 + (size_t)b * DO_ * N_;
    const uint16_t* PtB = Pt   + (size_t)b * M_  * N_;

    const int srow = tid >> 3;
    const int sseg = tid & 7;

    const int w  = tid >> 6;
    const int wd = w >> 1, wm = w & 1;
    const int l  = tid & 63;
    const int lr = l & 15;
    const int lg = l >> 4;

    f32x4 acc[4][4] = {};

    for (int n0 = sk * KCHUNK_; n0 < (sk + 1) * KCHUNK_; n0 += 64) {
        #pragma unroll
        for (int i = 0; i < 4; ++i) {
            int r = srow + i * 32;
            *(bf16x8*)&Asm[r * 88 + sseg * 8] =
                *(const bf16x8*)&moB[(size_t)(d0 + r) * N_ + n0 + sseg * 8];
            *(bf16x8*)&Psm[r * 88 + sseg * 8] =
                *(const bf16x8*)&PtB[(size_t)(m0 + r) * N_ + n0 + sseg * 8];
        }
        __syncthreads();
        #pragma unroll
        for (int kk = 0; kk < 64; kk += 32) {
            bf16x8 a[4], p[4];
            #pragma unroll
            for (int i = 0; i < 4; ++i)
                a[i] = *(const bf16x8*)&Asm[(wd * 64 + i * 16 + lr) * 88 + kk + lg * 8];
            #pragma unroll
            for (int j = 0; j < 4; ++j)
                p[j] = *(const bf16x8*)&Psm[(wm * 64 + j * 16 + lr) * 88 + kk + lg * 8];
            #pragma unroll
            for (int i = 0; i < 4; ++i)
                #pragma unroll
                for (int j = 0; j < 4; ++j)
                    acc[i][j] = __builtin_amdgcn_mfma_f32_16x16x32_bf16(
                        a[i], p[j], acc[i][j], 0, 0, 0);
        }
        __syncthreads();
    }

    float* pp = part + ((size_t)(sk * B_ + b) * DO_ + d0) * M_;
    #pragma unroll
    for (int i = 0; i < 4; ++i)
        #pragma unroll
        for (int j = 0; j < 4; ++j)
            #pragma unroll
            for (int r = 0; r < 4; ++r) {
                int d = wd * 64 + i * 16 + lg * 4 + r;   // C/D row (m89-verified)
                int m = wm * 64 + j * 16 + lr;           // C/D col = lane&15
                pp[(size_t)d * M_ + m0 + m] = acc[i][j][r];
            }
}

// ---------------------------------------------------------------------------
// Kernel 7 (fast path): sum the 4 split-K partials into out channels [0,DO).
// ---------------------------------------------------------------------------
__global__ __launch_bounds__(256) void k_pvreduce(const float* __restrict__ part,
                                                  float* __restrict__ out) {
    constexpr size_t OUTSZ = (size_t)B_ * DO_ * M_;
    const size_t i = (size_t)blockIdx.x * 256 + threadIdx.x;
    const size_t e = i * 4;
    float4 a = *(const float4*)&part[e];
    float4 b = *(const float4*)&part[OUTSZ + e];
    float4 c = *(const float4*)&part[2 * OUTSZ + e];
    float4 d = *(const float4*)&part[3 * OUTSZ + e];
    a.x += b.x + c.x + d.x;
    a.y += b.y + c.y + d.y;
    a.z += b.z + c.z + d.z;
    a.w += b.w + c.w + d.w;
    const int bb = (int)(e / ((size_t)DO_ * M_));
    const size_t rem = e % ((size_t)DO_ * M_);
    *(float4*)&out[(size_t)bb * 2 * DO_ * M_ + rem] = a;
}

// ---------------------------------------------------------------------------
// Fallback fp32 kernels (used when ws_size is too small for the MFMA path)
// ---------------------------------------------------------------------------
__global__ __launch_bounds__(256) void k_scores(const float* __restrict__ mi,
                                                const float* __restrict__ qi,
                                                float* __restrict__ S) {
    __shared__ float As[32][64];
    __shared__ float Bs[32][64];
    const int m0 = blockIdx.x * 64;
    const int n0 = blockIdx.y * 64;
    const int b  = blockIdx.z;
    const int tid = threadIdx.x;
    const int tx = tid & 15;
    const int ty = tid >> 4;

    const float* miB = mi + (size_t)b * DE_ * N_;
    const float* qiB = qi + (size_t)b * DE_ * M_;

    float acc[4][4] = {};

    for (int k0 = 0; k0 < DE_; k0 += 32) {
        #pragma unroll
        for (int t = 0; t < 8; ++t) {
            int e = tid + t * 256;
            int kk = e >> 6, nn = e & 63;
            As[kk][nn] = miB[(size_t)(k0 + kk) * N_ + n0 + nn];
            Bs[kk][nn] = qiB[(size_t)(k0 + kk) * M_ + m0 + nn];
        }
        __syncthreads();
        #pragma unroll
        for (int kk = 0; kk < 32; ++kk) {
            float a[4], p[4];
            #pragma unroll
            for (int i = 0; i < 4; ++i) a[i] = As[kk][ty * 4 + i];
            #pragma unroll
            for (int j = 0; j < 4; ++j) p[j] = Bs[kk][tx * 4 + j];
            #pragma unroll
            for (int i = 0; i < 4; ++i)
                #pragma unroll
                for (int j = 0; j < 4; ++j)
                    acc[i][j] = fmaf(a[i], p[j], acc[i][j]);
        }
        __syncthreads();
    }

    const float scale = 0.08838834764831845f;
    float* Sp = S + (size_t)b * N_ * M_;
    #pragma unroll
    for (int i = 0; i < 4; ++i) {
        float4 v = make_float4(acc[i][0] * scale, acc[i][1] * scale,
                               acc[i][2] * scale, acc[i][3] * scale);
        *(float4*)&Sp[(size_t)(n0 + ty * 4 + i) * M_ + m0 + tx * 4] = v;
    }
}

__global__ __launch_bounds__(256) void k_colstats(const float* __restrict__ S,
                                                  float* __restrict__ pmax,
                                                  float* __restrict__ psum) {
    const int m = blockIdx.x * 256 + threadIdx.x;
    const int c = blockIdx.y;
    const int b = blockIdx.z;
    const float* Sp = S + (size_t)b * N_ * M_ + (size_t)c * 256 * M_ + m;
    float mx = -INFINITY, sm = 0.f;
    for (int n = 0; n < 256; ++n) {
        float x = Sp[(size_t)n * M_];
        float mnew = fmaxf(mx, x);
        sm = sm * __expf(mx - mnew) + __expf(x - mnew);
        mx = mnew;
    }
    size_t idx = ((size_t)b * NCHUNK_ + c) * M_ + m;
    pmax[idx] = mx;
    psum[idx] = sm;
}

__global__ __launch_bounds__(256) void k_reduce(const float* __restrict__ pmax,
                                                const float* __restrict__ psum,
                                                float* __restrict__ gmax,
                                                float* __restrict__ ginv) {
    const int g = blockIdx.x * 256 + threadIdx.x;
    const int b = g >> 10;
    const int m = g & (M_ - 1);
    float pm[NCHUNK_];
    float mx = -INFINITY;
    #pragma unroll
    for (int c = 0; c < NCHUNK_; ++c) {
        pm[c] = pmax[((size_t)b * NCHUNK_ + c) * M_ + m];
        mx = fmaxf(mx, pm[c]);
    }
    float sm = 0.f;
    #pragma unroll
    for (int c = 0; c < NCHUNK_; ++c) {
        sm += psum[((size_t)b * NCHUNK_ + c) * M_ + m] * __expf(pm[c] - mx);
    }
    gmax[g] = mx;
    ginv[g] = 1.0f / sm;
}

__global__ __launch_bounds__(256) void k_normalize(float* __restrict__ S,
                                                   const float* __restrict__ gmax,
                                                   const float* __restrict__ ginv) {
    const size_t total4 = (size_t)B_ * N_ * M_ / 4;
    for (size_t i = (size_t)blockIdx.x * 256 + threadIdx.x; i < total4;
         i += (size_t)gridDim.x * 256) {
        size_t e = i * 4;
        int b = (int)(e / ((size_t)N_ * M_));
        int m = (int)(e & (M_ - 1));
        float4 v = ((float4*)S)[i];
        float4 gm = *(const float4*)&gmax[b * M_ + m];
        float4 gi = *(const float4*)&ginv[b * M_ + m];
        v.x = __expf(v.x - gm.x) * gi.x;
        v.y = __expf(v.y - gm.y) * gi.y;
        v.z = __expf(v.z - gm.z) * gi.z;
        v.w = __expf(v.w - gm.w) * gi.w;
        ((float4*)S)[i] = v;
    }
}

__global__ __launch_bounds__(256) void k_pv(const float* __restrict__ mo,
                                            const float* __restrict__ P,
                                            float* __restrict__ out) {
    __shared__ float As[32][68];
    __shared__ float Ps[32][64];
    const int m0 = blockIdx.x * 64;
    const int d0 = blockIdx.y * 64;
    const int b  = blockIdx.z;
    const int tid = threadIdx.x;
    const int tx = tid & 15;
    const int ty = tid >> 4;

    const float* moB = mo + (size_t)b * DO_ * N_;
    const float* PB  = P  + (size_t)b * N_ * M_;

    float acc[4][4] = {};

    for (int n0 = 0; n0 < N_; n0 += 32) {
        #pragma unroll
        for (int t = 0; t < 8; ++t) {
            int e = tid + t * 256;
            int dd = e >> 5, nn = e & 31;
            As[nn][dd] = moB[(size_t)(d0 + dd) * N_ + n0 + nn];
        }
        #pragma unroll
        for (int t = 0; t < 8; ++t) {
            int e = tid + t * 256;
            int kk = e >> 6, mm = e & 63;
            Ps[kk][mm] = PB[(size_t)(n0 + kk) * M_ + m0 + mm];
        }
        __syncthreads();
        #pragma unroll
        for (int kk = 0; kk < 32; ++kk) {
            float a[4], p[4];
            #pragma unroll
            for (int i = 0; i < 4; ++i) a[i] = As[kk][ty * 4 + i];
            #pragma unroll
            for (int j = 0; j < 4; ++j) p[j] = Ps[kk][tx * 4 + j];
            #pragma unroll
            for (int i = 0; i < 4; ++i)
                #pragma unroll
                for (int j = 0; j < 4; ++j)
                    acc[i][j] = fmaf(a[i], p[j], acc[i][j]);
        }
        __syncthreads();
    }

    float* outB = out + (size_t)b * 2 * DO_ * M_;
    #pragma unroll
    for (int i = 0; i < 4; ++i) {
        float4 v = make_float4(acc[i][0], acc[i][1], acc[i][2], acc[i][3]);
        *(float4*)&outB[(size_t)(d0 + ty * 4 + i) * M_ + m0 + tx * 4] = v;
    }
}

// ---------------------------------------------------------------------------
// Kernel 8: copy query_out into channels [DO, 2*DO).
// ---------------------------------------------------------------------------
__global__ __launch_bounds__(256) void k_copyq(const float* __restrict__ q,
                                               float* __restrict__ out) {
    const size_t i = (size_t)blockIdx.x * 256 + threadIdx.x;
    const size_t e = i * 4;
    const int b = (int)(e / ((size_t)DO_ * M_));
    const size_t r = e % ((size_t)DO_ * M_);
    float4 v = *(const float4*)&q[e];
    *(float4*)&out[(size_t)b * 2 * DO_ * M_ + (size_t)DO_ * M_ + r] = v;
}

// ---------------------------------------------------------------------------
extern "C" void kernel_launch(void* const* d_in, const int* in_sizes, int n_in,
                              void* d_out, int out_size, void* d_ws, size_t ws_size,
                              hipStream_t stream) {
    const float* mi = (const float*)d_in[0];  // memory_in  [B,128,8192]
    const float* mo = (const float*)d_in[1];  // memory_out [B,512,8192]
    const float* qi = (const float*)d_in[2];  // query_in   [B,128,1024]
    const float* qo = (const float*)d_in[3];  // query_out  [B,512,1024]

    float* out  = (float*)d_out;                       // [B,1024,1024]
    float* prob = out + (size_t)B_ * 2 * DO_ * M_;     // [B,8192,1024]

    // workspace layout (fast path)
    float* pmax2 = (float*)d_ws;                       // [B,64,M]
    float* psum2 = pmax2 + (size_t)B_ * NT_ * M_;      // [B,64,M]
    float* gmax  = psum2 + (size_t)B_ * NT_ * M_;      // [B,M]
    float* ginv  = gmax + (size_t)B_ * M_;             // [B,M]
    uint16_t* Pt   = (uint16_t*)(ginv + B_ * M_);      // [B,M,N] bf16 transposed prob
    uint16_t* mo16 = Pt + (size_t)B_ * M_ * N_;        // [B,DO,N] bf16
    float*    part = (float*)(mo16 + (size_t)B_ * DO_ * N_);  // [SPLITK,B,DO,M]
    uint16_t* mit  = (uint16_t*)(part + (size_t)SPLITK_ * B_ * DO_ * M_); // [B,N,DE]
    uint16_t* qit  = mit + (size_t)B_ * N_ * DE_;      // [B,M,DE]
    const size_t need_full =
        (size_t)((char*)(qit + (size_t)B_ * M_ * DE_) - (char*)d_ws);

    if (ws_size >= need_full) {
        // --- fully fused MFMA path ---
        k_tconv     <<<dim3(N_ / 64, B_), 256, 0, stream>>>(mi, mit, N_);
        k_tconv     <<<dim3(M_ / 64, B_), 256, 0, stream>>>(qi, qit, M_);
        k_stats_mfma<<<dim3(M_ / 128, N_ / 128, B_), 256, 0, stream>>>(mit, qit, pmax2, psum2);
        k_reduce2   <<<dim3(B_ * M_ / 256), 256, 0, stream>>>(pmax2, psum2, gmax, ginv);
        k_moconv    <<<dim3((B_ * DO_ * N_ / 16) / 256), 256, 0, stream>>>(mo, mo16);
        k_prob_mfma <<<dim3(M_ / 128, N_ / 128, B_), 256, 0, stream>>>(mit, qit, gmax, ginv, prob, Pt);
        k_pv_mfma   <<<dim3(M_ / 128, DO_ / 128, B_ * SPLITK_), 256, 0, stream>>>(mo16, Pt, part);
        k_pvreduce  <<<dim3((B_ * DO_ * M_ / 4) / 256), 256, 0, stream>>>(part, out);
    } else {
        // --- fp32 fallback path ---
        float* pmax = pmax2;                            // reuse layout
        float* psum = pmax + (size_t)B_ * NCHUNK_ * M_;
        float* gm2  = psum + (size_t)B_ * NCHUNK_ * M_;
        float* gi2  = gm2 + B_ * M_;
        k_scores   <<<dim3(M_ / 64, N_ / 64, B_), 256, 0, stream>>>(mi, qi, prob);
        k_colstats <<<dim3(M_ / 256, NCHUNK_, B_), 256, 0, stream>>>(prob, pmax, psum);
        k_reduce   <<<dim3(B_ * M_ / 256), 256, 0, stream>>>(pmax, psum, gm2, gi2);
        k_normalize<<<dim3(2048), 256, 0, stream>>>(prob, gm2, gi2);
        k_pv       <<<dim3(M_ / 64, DO_ / 64, B_), 256, 0, stream>>>(mo, prob, out);
    }
    k_copyq<<<dim3((B_ * DO_ * M_ / 4) / 256), 256, 0, stream>>>(qo, out);
}